// Round 1
// baseline (157.284 us; speedup 1.0000x reference)
//
#include <hip/hip_runtime.h>

// AdaptiveGN_Patches_Hadamart: per-patch GroupNorm + silu-gate, fp32.
// Layout insight: patchify -> groupnorm -> de-patchify is spatially identity,
// so each block handles one (batch, patch_i, patch_j, group) = 4 channels x
// 64x64 patch = 16384 floats, staged in registers (no x re-read from HBM).

constexpr int CHANNELS = 128;
constexpr int HW = 256;
constexpr int NP = 4;
constexpr int P = 64;
constexpr int G = 32;
constexpr int CPG = CHANNELS / G;          // 4 channels per group
constexpr float EPS = 1e-5f;
// elements per group = CPG * P * P = 16384 = 512 threads * 8 float4

__global__ __launch_bounds__(512, 4)
void gn_patch_gate_kernel(const float* __restrict__ x,
                          const float* __restrict__ y,
                          const float* __restrict__ wgt,
                          const float* __restrict__ bvec,
                          float* __restrict__ out)
{
    const int bid = blockIdx.x;
    const int g  = bid & 31;          // group
    const int pj = (bid >> 5) & 3;    // patch col
    const int pi = (bid >> 7) & 3;    // patch row
    const int b  = bid >> 9;          // batch
    const int tid = threadIdx.x;

    const unsigned cstride = HW * HW; // 65536 floats per channel plane
    const unsigned base =
        (((unsigned)b * CHANNELS + (unsigned)g * CPG) * HW + (unsigned)pi * P) * HW
        + (unsigned)pj * P;

    // Phase 1: load this group's x into registers, accumulate sum / sumsq.
    float4 xv[8];
    unsigned addr[8];
    float s = 0.f, ss = 0.f;
#pragma unroll
    for (int k = 0; k < 8; ++k) {
        const unsigned u  = (unsigned)tid + (unsigned)(k << 9); // float4 idx [0,4096)
        const unsigned cc = u >> 10;        // channel within group (1024 f4/chan)
        const unsigned r  = (u >> 4) & 63;  // row within patch (16 f4/row)
        const unsigned c4 = u & 15;         // float4 col
        const unsigned a  = base + cc * cstride + r * HW + (c4 << 2);
        addr[k] = a;
        const float4 v = *reinterpret_cast<const float4*>(x + a);
        xv[k] = v;
        s  += (v.x + v.y) + (v.z + v.w);
        ss += (v.x * v.x + v.y * v.y) + (v.z * v.z + v.w * v.w);
    }

    // Wave (64-lane) butterfly reduce, then cross-wave via LDS.
#pragma unroll
    for (int off = 32; off; off >>= 1) {
        s  += __shfl_xor(s, off);
        ss += __shfl_xor(ss, off);
    }
    __shared__ float red[16];
    const int wv = tid >> 6;
    if ((tid & 63) == 0) { red[wv] = s; red[8 + wv] = ss; }
    __syncthreads();
    float ts = 0.f, tss = 0.f;
#pragma unroll
    for (int q = 0; q < 8; ++q) { ts += red[q]; tss += red[8 + q]; }

    const float inv_n = 1.0f / 16384.0f;
    const float mean = ts * inv_n;
    const float var  = fmaxf(tss * inv_n - mean * mean, 0.f);
    const float rstd = rsqrtf(var + EPS);

    // Per-channel affine folded into scale/shift.
    float scl[CPG], sft[CPG];
#pragma unroll
    for (int cc = 0; cc < CPG; ++cc) {
        const float wc = wgt[g * CPG + cc];
        scl[cc] = wc * rstd;
        sft[cc] = bvec[g * CPG + cc] - mean * rstd * wc;
    }

    // Phase 2: normalize (from registers), gate with 1 + silu(y), store.
#pragma unroll
    for (int k = 0; k < 8; ++k) {
        const unsigned u  = (unsigned)tid + (unsigned)(k << 9);
        const unsigned cc = u >> 10;
        const unsigned a  = addr[k];
        const float4 yv = *reinterpret_cast<const float4*>(y + a);
        float4 o;
        {
            const float xn = xv[k].x * scl[cc] + sft[cc];
            o.x = xn * (1.f + yv.x / (1.f + expf(-yv.x)));
        }
        {
            const float xn = xv[k].y * scl[cc] + sft[cc];
            o.y = xn * (1.f + yv.y / (1.f + expf(-yv.y)));
        }
        {
            const float xn = xv[k].z * scl[cc] + sft[cc];
            o.z = xn * (1.f + yv.z / (1.f + expf(-yv.z)));
        }
        {
            const float xn = xv[k].w * scl[cc] + sft[cc];
            o.w = xn * (1.f + yv.w / (1.f + expf(-yv.w)));
        }
        *reinterpret_cast<float4*>(out + a) = o;
    }
}

extern "C" void kernel_launch(void* const* d_in, const int* in_sizes, int n_in,
                              void* d_out, int out_size, void* d_ws, size_t ws_size,
                              hipStream_t stream) {
    const float* x    = (const float*)d_in[0];
    const float* y    = (const float*)d_in[1];
    const float* wgt  = (const float*)d_in[2];
    const float* bvec = (const float*)d_in[3];
    float* out = (float*)d_out;

    const int B = in_sizes[0] / (CHANNELS * HW * HW);   // 8
    const int nblocks = B * NP * NP * G;                // 4096
    gn_patch_gate_kernel<<<dim3(nblocks), dim3(512), 0, stream>>>(x, y, wgt, bvec, out);
}

// Round 2
// 153.092 us; speedup vs baseline: 1.0274x; 1.0274x over previous
//
#include <hip/hip_runtime.h>

// AdaptiveGN_Patches_Hadamart: per-patch GroupNorm + silu-gate, fp32.
// Patchify -> groupnorm -> de-patchify is spatially identity, so each block
// handles one (batch, patch_i, patch_j, group) = 4 channels x 64x64 patch
// = 16384 floats. R1: stage x in LDS (compiler demoted register staging to a
// global re-read in R0 — VGPR_Count 36 proved it), and use fast exp2/rcp silu
// instead of expf + precise division.

constexpr int CHANNELS = 128;
constexpr int HW = 256;
constexpr int NP = 4;
constexpr int G = 32;
constexpr int CPG = CHANNELS / G;          // 4 channels per group
constexpr float EPS = 1e-5f;
// elements per group = CPG * 64 * 64 = 16384 = 512 threads * 8 float4

__device__ __forceinline__ float fast_gate(float v) {
    // 1 + silu(v) = 1 + v / (1 + exp(-v)); exp(-v) = exp2(-v*log2(e))
    const float e = __builtin_amdgcn_exp2f(v * -1.44269504088896f);
    return 1.0f + v * __builtin_amdgcn_rcpf(1.0f + e);
}

__global__ __launch_bounds__(512, 2)
void gn_patch_gate_kernel(const float* __restrict__ x,
                          const float* __restrict__ y,
                          const float* __restrict__ wgt,
                          const float* __restrict__ bvec,
                          float* __restrict__ out)
{
    __shared__ float4 xs[4096];     // 64 KB: the whole group's x tile
    __shared__ float red[16];

    const int bid = blockIdx.x;
    const int g  = bid & 31;          // group
    const int pj = (bid >> 5) & 3;    // patch col
    const int pi = (bid >> 7) & 3;    // patch row
    const int b  = bid >> 9;          // batch
    const int tid = threadIdx.x;

    const unsigned cstride = HW * HW; // 65536 floats per channel plane
    const unsigned base =
        (((unsigned)b * CHANNELS + (unsigned)g * CPG) * HW + (unsigned)pi * 64) * HW
        + (unsigned)pj * 64;

    // Phase 1: load x, stash in LDS, accumulate sum / sumsq.
    float s = 0.f, ss = 0.f;
#pragma unroll
    for (int k = 0; k < 8; ++k) {
        const unsigned u  = (unsigned)tid + (unsigned)(k << 9); // float4 idx [0,4096)
        const unsigned cc = u >> 10;        // channel within group (1024 f4/chan)
        const unsigned r  = (u >> 4) & 63;  // row within patch (16 f4/row)
        const unsigned c4 = u & 15;         // float4 col
        const unsigned a  = base + cc * cstride + r * HW + (c4 << 2);
        const float4 v = *reinterpret_cast<const float4*>(x + a);
        xs[u] = v;
        s  += (v.x + v.y) + (v.z + v.w);
        ss += (v.x * v.x + v.y * v.y) + (v.z * v.z + v.w * v.w);
    }

    // Wave (64-lane) butterfly reduce, then cross-wave via LDS.
#pragma unroll
    for (int off = 32; off; off >>= 1) {
        s  += __shfl_xor(s, off);
        ss += __shfl_xor(ss, off);
    }
    const int wv = tid >> 6;
    if ((tid & 63) == 0) { red[wv] = s; red[8 + wv] = ss; }
    __syncthreads();
    float ts = 0.f, tss = 0.f;
#pragma unroll
    for (int q = 0; q < 8; ++q) { ts += red[q]; tss += red[8 + q]; }

    const float inv_n = 1.0f / 16384.0f;
    const float mean = ts * inv_n;
    const float var  = fmaxf(tss * inv_n - mean * mean, 0.f);
    const float rstd = rsqrtf(var + EPS);

    // Per-channel affine folded into scale/shift.
    float scl[CPG], sft[CPG];
#pragma unroll
    for (int cc = 0; cc < CPG; ++cc) {
        const float wc = wgt[g * CPG + cc];
        scl[cc] = wc * rstd;
        sft[cc] = bvec[g * CPG + cc] - mean * rstd * wc;
    }

    // Phase 2: normalize from LDS, gate with 1 + silu(y), store.
#pragma unroll
    for (int k = 0; k < 8; ++k) {
        const unsigned u  = (unsigned)tid + (unsigned)(k << 9);
        const unsigned cc = u >> 10;
        const unsigned r  = (u >> 4) & 63;
        const unsigned c4 = u & 15;
        const unsigned a  = base + cc * cstride + r * HW + (c4 << 2);
        const float4 yv = *reinterpret_cast<const float4*>(y + a);
        const float4 v  = xs[u];
        float4 o;
        o.x = (v.x * scl[cc] + sft[cc]) * fast_gate(yv.x);
        o.y = (v.y * scl[cc] + sft[cc]) * fast_gate(yv.y);
        o.z = (v.z * scl[cc] + sft[cc]) * fast_gate(yv.z);
        o.w = (v.w * scl[cc] + sft[cc]) * fast_gate(yv.w);
        *reinterpret_cast<float4*>(out + a) = o;
    }
}

extern "C" void kernel_launch(void* const* d_in, const int* in_sizes, int n_in,
                              void* d_out, int out_size, void* d_ws, size_t ws_size,
                              hipStream_t stream) {
    const float* x    = (const float*)d_in[0];
    const float* y    = (const float*)d_in[1];
    const float* wgt  = (const float*)d_in[2];
    const float* bvec = (const float*)d_in[3];
    float* out = (float*)d_out;

    const int B = in_sizes[0] / (CHANNELS * HW * HW);   // 8
    const int nblocks = B * NP * NP * G;                // 4096
    gn_patch_gate_kernel<<<dim3(nblocks), dim3(512), 0, stream>>>(x, y, wgt, bvec, out);
}

// Round 5
// 151.477 us; speedup vs baseline: 1.0383x; 1.0107x over previous
//
#include <hip/hip_runtime.h>

// AdaptiveGN_Patches_Hadamart: per-patch GroupNorm + silu-gate, fp32.
// Each block = one (batch, patch_i, patch_j, group): 4 channels x 64x64 patch
// = 16384 floats. x staged in LDS (single HBM read); y PREFETCHED into
// registers during phase 1, pinned per-SCALAR with "+v" (multi-reg float4
// ties are unsupported "indirect register inputs"); out stored non-temporally
// (native ext_vector_type — builtin rejects HIP_vector_type).

constexpr int CHANNELS = 128;
constexpr int HW = 256;
constexpr int NP = 4;
constexpr int G = 32;
constexpr int CPG = CHANNELS / G;          // 4 channels per group
constexpr float EPS = 1e-5f;
// elements per group = CPG * 64 * 64 = 16384 = 512 threads * 8 float4

typedef float f32x4 __attribute__((ext_vector_type(4)));

__device__ __forceinline__ float fast_gate(float v) {
    // 1 + silu(v) = 1 + v / (1 + exp(-v)); exp(-v) = exp2(-v*log2(e))
    const float e = __builtin_amdgcn_exp2f(v * -1.44269504088896f);
    return 1.0f + v * __builtin_amdgcn_rcpf(1.0f + e);
}

__global__ __launch_bounds__(512, 4)
void gn_patch_gate_kernel(const float* __restrict__ x,
                          const float* __restrict__ y,
                          const float* __restrict__ wgt,
                          const float* __restrict__ bvec,
                          float* __restrict__ out)
{
    __shared__ float4 xs[4096];     // 64 KB: the whole group's x tile
    __shared__ float red[16];

    const int bid = blockIdx.x;
    const int g  = bid & 31;          // group
    const int pj = (bid >> 5) & 3;    // patch col
    const int pi = (bid >> 7) & 3;    // patch row
    const int b  = bid >> 9;          // batch
    const int tid = threadIdx.x;

    const unsigned cstride = HW * HW; // 65536 floats per channel plane
    const unsigned base =
        (((unsigned)b * CHANNELS + (unsigned)g * CPG) * HW + (unsigned)pi * 64) * HW
        + (unsigned)pj * 64;

    // Phase 1: load x -> LDS + partial sums; issue y loads, pin scalars.
    float y0[8], y1[8], y2[8], y3[8];
    unsigned addr[8];
    float s = 0.f, ss = 0.f;
#pragma unroll
    for (int k = 0; k < 8; ++k) {
        const unsigned u  = (unsigned)tid + (unsigned)(k << 9); // float4 idx [0,4096)
        const unsigned cc = u >> 10;        // channel within group (1024 f4/chan)
        const unsigned r  = (u >> 4) & 63;  // row within patch (16 f4/row)
        const unsigned c4 = u & 15;         // float4 col
        const unsigned a  = base + cc * cstride + r * HW + (c4 << 2);
        addr[k] = a;
        const float4 v = *reinterpret_cast<const float4*>(x + a);
        const float4 w = *reinterpret_cast<const float4*>(y + a);
        float w0 = w.x, w1 = w.y, w2 = w.z, w3 = w.w;
        asm volatile("" : "+v"(w0), "+v"(w1), "+v"(w2), "+v"(w3)); // no remat
        y0[k] = w0; y1[k] = w1; y2[k] = w2; y3[k] = w3;
        xs[u] = v;
        s  += (v.x + v.y) + (v.z + v.w);
        ss += (v.x * v.x + v.y * v.y) + (v.z * v.z + v.w * v.w);
    }

    // Wave (64-lane) butterfly reduce, then cross-wave via LDS.
#pragma unroll
    for (int off = 32; off; off >>= 1) {
        s  += __shfl_xor(s, off);
        ss += __shfl_xor(ss, off);
    }
    const int wv = tid >> 6;
    if ((tid & 63) == 0) { red[wv] = s; red[8 + wv] = ss; }
    __syncthreads();
    float ts = 0.f, tss = 0.f;
#pragma unroll
    for (int q = 0; q < 8; ++q) { ts += red[q]; tss += red[8 + q]; }

    const float inv_n = 1.0f / 16384.0f;
    const float mean = ts * inv_n;
    const float var  = fmaxf(tss * inv_n - mean * mean, 0.f);
    const float rstd = rsqrtf(var + EPS);

    // Per-channel affine folded into scale/shift.
    float scl[CPG], sft[CPG];
#pragma unroll
    for (int cc = 0; cc < CPG; ++cc) {
        const float wc = wgt[g * CPG + cc];
        scl[cc] = wc * rstd;
        sft[cc] = bvec[g * CPG + cc] - mean * rstd * wc;
    }

    // Phase 2: normalize from LDS, gate with prefetched y, nontemporal store.
#pragma unroll
    for (int k = 0; k < 8; ++k) {
        const unsigned u  = (unsigned)tid + (unsigned)(k << 9);
        const unsigned cc = u >> 10;
        const float4 v  = xs[u];
        f32x4 o;
        o.x = (v.x * scl[cc] + sft[cc]) * fast_gate(y0[k]);
        o.y = (v.y * scl[cc] + sft[cc]) * fast_gate(y1[k]);
        o.z = (v.z * scl[cc] + sft[cc]) * fast_gate(y2[k]);
        o.w = (v.w * scl[cc] + sft[cc]) * fast_gate(y3[k]);
        __builtin_nontemporal_store(o, reinterpret_cast<f32x4*>(out + addr[k]));
    }
}

extern "C" void kernel_launch(void* const* d_in, const int* in_sizes, int n_in,
                              void* d_out, int out_size, void* d_ws, size_t ws_size,
                              hipStream_t stream) {
    const float* x    = (const float*)d_in[0];
    const float* y    = (const float*)d_in[1];
    const float* wgt  = (const float*)d_in[2];
    const float* bvec = (const float*)d_in[3];
    float* out = (float*)d_out;

    const int B = in_sizes[0] / (CHANNELS * HW * HW);   // 8
    const int nblocks = B * NP * NP * G;                // 4096
    gn_patch_gate_kernel<<<dim3(nblocks), dim3(512), 0, stream>>>(x, y, wgt, bvec, out);
}